// Round 1
// baseline (138.376 us; speedup 1.0000x reference)
//
#include <hip/hip_runtime.h>

// ChamferDistance2D: B=8, N=M=8192, fp32, scalar output.
// cost = sum_b [ mean_i min_j d(i,j) + mean_j min_i d(i,j) ],  d = squared L2.
// Strategy: d(i,j) = |p1_i|^2 + (|p2_j|^2 - 2 p1_i . p2_j).
//   Inner term t = fma(-2y1, y2, fma(-2x1, x2, sq2)) -> 2 FMA + min per pair.
//   Stage (x2, y2, sq2, 0) float4 chunks in LDS (broadcast reads, conflict-free).
//   IPT=16 points/thread amortizes the broadcast ds_read_b128 (VALU:LDS ~ 320:192 cyc/CU).
//   j-split S=16 for parallelism: exact fp32 partial mins to d_ws (8 MB), no atomics.

#define BATCH 8
#define NPTS  8192            // points per batch, both sets
#define TPB   256             // threads per block
#define IPT   16              // points per thread
#define PPB   (TPB * IPT)     // 4096 points per block
#define TILES (NPTS / PPB)    // 2 point-tiles per batch
#define S     16              // j-splits
#define JCH   (NPTS / S)      // 512 j's per block (fits LDS in one chunk)

// grid.x = 2 * BATCH * TILES * S = 512
__global__ __launch_bounds__(TPB, 2)
void chamfer_partial(const float* __restrict__ p1, const float* __restrict__ p2,
                     float* __restrict__ partial /* [2][B][S][N] */) {
    __shared__ float4 q[JCH];  // 8 KB: (x, y, |p|^2, pad)

    int blk = blockIdx.x;
    int split = blk & (S - 1);      blk >>= 4;
    int tile  = blk & (TILES - 1);  blk >>= 1;
    int b     = blk & (BATCH - 1);  blk >>= 3;
    int dir   = blk;                // 0: min over p2 for each p1; 1: swapped

    const float2* a  = (const float2*)(dir ? p2 : p1) + (size_t)b * NPTS;
    const float2* bp = (const float2*)(dir ? p1 : p2) + (size_t)b * NPTS + split * JCH;

    int t = threadIdx.x;

    // stage this split's j-chunk into LDS with precomputed |p|^2
    for (int j = t; j < JCH; j += TPB) {
        float2 v = bp[j];
        q[j] = make_float4(v.x, v.y, fmaf(v.x, v.x, v.y * v.y), 0.0f);
    }

    // load my 16 points into registers (coalesced: stride TPB)
    int pt_base = tile * PPB;
    float xp[IPT], yp[IPT], m[IPT];
#pragma unroll
    for (int k = 0; k < IPT; ++k) {
        float2 v = a[pt_base + k * TPB + t];
        xp[k] = -2.0f * v.x;
        yp[k] = -2.0f * v.y;
        m[k]  = 3.0e38f;
    }

    __syncthreads();

    // main loop: 2 broadcast float4 reads + 16 * (4 fma + 1 min + 1 min3) per step
    for (int j = 0; j < JCH; j += 2) {
        float4 q0 = q[j];
        float4 q1 = q[j + 1];
#pragma unroll
        for (int k = 0; k < IPT; ++k) {
            float t0 = fmaf(yp[k], q0.y, fmaf(xp[k], q0.x, q0.z));
            float t1 = fmaf(yp[k], q1.y, fmaf(xp[k], q1.x, q1.z));
            m[k] = fminf(m[k], fminf(t0, t1));   // -> v_min3_f32
        }
    }

    // write partial mins (exact fp32, no atomics); coalesced per k
    float* out = partial + ((size_t)(dir * BATCH + b) * S + split) * NPTS + pt_base;
#pragma unroll
    for (int k = 0; k < IPT; ++k)
        out[k * TPB + t] = m[k];
}

// grid.x = 2 * BATCH * NPTS / TPB = 512
__global__ __launch_bounds__(TPB)
void chamfer_reduce(const float* __restrict__ p1, const float* __restrict__ p2,
                    const float* __restrict__ partial, float* __restrict__ out) {
    int gid   = blockIdx.x * TPB + threadIdx.x;  // 0 .. 2*B*N
    int point = gid & (NPTS - 1);
    int rest  = gid >> 13;                       // NPTS = 2^13
    int b     = rest & (BATCH - 1);
    int dir   = rest >> 3;

    const float* base = partial + ((size_t)(dir * BATCH + b) * S) * NPTS + point;
    float m = base[0];
#pragma unroll
    for (int s = 1; s < S; ++s)
        m = fminf(m, base[(size_t)s * NPTS]);

    float2 v = ((const float2*)(dir ? p2 : p1))[(size_t)b * NPTS + point];
    float d = m + fmaf(v.x, v.x, v.y * v.y);     // + |p1_i|^2

    // wave(64) shuffle reduce, then cross-wave via LDS
#pragma unroll
    for (int off = 32; off > 0; off >>= 1)
        d += __shfl_down(d, off, 64);

    __shared__ float wsum[TPB / 64];
    int lane = threadIdx.x & 63;
    int w    = threadIdx.x >> 6;
    if (lane == 0) wsum[w] = d;
    __syncthreads();
    if (threadIdx.x == 0) {
        float ssum = wsum[0] + wsum[1] + wsum[2] + wsum[3];
        atomicAdd(out, ssum * (1.0f / NPTS));
    }
}

extern "C" void kernel_launch(void* const* d_in, const int* in_sizes, int n_in,
                              void* d_out, int out_size, void* d_ws, size_t ws_size,
                              hipStream_t stream) {
    const float* p1 = (const float*)d_in[0];
    const float* p2 = (const float*)d_in[1];
    float* out      = (float*)d_out;
    float* partial  = (float*)d_ws;   // needs 2*8*16*8192*4 = 8 MB

    hipMemsetAsync(d_out, 0, sizeof(float), stream);

    chamfer_partial<<<2 * BATCH * TILES * S, TPB, 0, stream>>>(p1, p2, partial);
    chamfer_reduce<<<2 * BATCH * NPTS / TPB, TPB, 0, stream>>>(p1, p2, partial, out);
}